// Round 6
// baseline (305.434 us; speedup 1.0000x reference)
//
#include <hip/hip_runtime.h>
#include <math.h>

// SFNAttention on MI355X (gfx950).
// R6: QKV GEMM -> 256x192 tile, 12 waves of 64x64 (4x3), 1 barrier + 1 vmcnt
//     per K-tile, both-sides XOR swizzle, full 256-block grid.
//     Attn -> NO K/V LDS staging (L2-resident after XCD swizzle): direct
//     global->reg loads, double-buffered one tile ahead, zero barriers.

typedef __bf16 bf16;
typedef bf16 bf16x4 __attribute__((ext_vector_type(4)));
typedef bf16 bf16x8 __attribute__((ext_vector_type(8)));
typedef float f32x4 __attribute__((ext_vector_type(4)));

#define LOG2E 1.4426950408889634f
#define MFMA16 __builtin_amdgcn_mfma_f32_16x16x32_bf16
#define S_WAITV(N) asm volatile("s_waitcnt vmcnt(" #N ")" ::: "memory")

__device__ __forceinline__ void bar() {
  asm volatile("" ::: "memory");
  __builtin_amdgcn_s_barrier();
  asm volatile("" ::: "memory");
}

__device__ __forceinline__ float sfn_f(float x) {
  return fminf(fmaxf(rintf(x + x), -8.0f), 8.0f) * 0.5f;
}

__device__ __forceinline__ void gload16(const bf16* g, bf16* l) {
  __builtin_amdgcn_global_load_lds((const __attribute__((address_space(1))) void*)g,
                                   (__attribute__((address_space(3))) void*)l, 16, 0, 0);
}

// ---------------- prep kernels ----------------

__global__ __launch_bounds__(256) void prep_x_kernel(const float* __restrict__ x,
                                                     bf16* __restrict__ ax) {
  int idx = blockIdx.x * 256 + threadIdx.x;   // 1,048,576 = 4096*1024/4
  int m  = idx >> 8;
  int kc = (idx & 255) << 2;
  const float4 v = *(const float4*)(x + (size_t)m * 1024 + kc);
  bf16 h0 = (bf16)v.x, h1 = (bf16)v.y, h2 = (bf16)v.z, h3 = (bf16)v.w;
  bf16 l0 = (bf16)(v.x - (float)h0), l1 = (bf16)(v.y - (float)h1),
       l2 = (bf16)(v.z - (float)h2), l3 = (bf16)(v.w - (float)h3);
  bf16x4 hv = {h0, h1, h2, h3};
  bf16x4 lv = {l0, l1, l2, l3};
  bf16* p = ax + (size_t)m * 3072 + kc;
  *(bf16x4*)(p)        = hv;
  *(bf16x4*)(p + 1024) = lv;
  *(bf16x4*)(p + 2048) = hv;
}

__global__ __launch_bounds__(256) void prep_w_kernel(const float* __restrict__ Wq,
                                                     const float* __restrict__ Wk,
                                                     const float* __restrict__ Wv,
                                                     bf16* __restrict__ wc) {
  int idx = blockIdx.x * 256 + threadIdx.x;   // 786,432 = 3*1024*1024/4
  int mat = idx >> 18;
  int r   = idx & 262143;
  int n   = r >> 8;
  int kc  = (r & 255) << 2;
  const float* W = (mat == 0) ? Wq : ((mat == 1) ? Wk : Wv);
  const float4 v = *(const float4*)(W + (size_t)n * 1024 + kc);
  bf16 h0 = (bf16)v.x, h1 = (bf16)v.y, h2 = (bf16)v.z, h3 = (bf16)v.w;
  bf16 l0 = (bf16)(v.x - (float)h0), l1 = (bf16)(v.y - (float)h1),
       l2 = (bf16)(v.z - (float)h2), l3 = (bf16)(v.w - (float)h3);
  bf16x4 hv = {h0, h1, h2, h3};
  bf16x4 lv = {l0, l1, l2, l3};
  bf16* p = wc + (size_t)(mat * 1024 + n) * 3072 + kc;
  *(bf16x4*)(p)        = hv;
  *(bf16x4*)(p + 1024) = hv;
  *(bf16x4*)(p + 2048) = lv;
}

__global__ __launch_bounds__(256) void prep_wo_kernel(const float* __restrict__ Wo,
                                                      bf16* __restrict__ wob) {
  int idx = blockIdx.x * 256 + threadIdx.x;   // 262,144 = 1024*1024/4
  const float4 v = *(const float4*)(Wo + (size_t)idx * 4);
  bf16x4 hv = {(bf16)v.x, (bf16)v.y, (bf16)v.z, (bf16)v.w};
  *(bf16x4*)(wob + (size_t)idx * 4) = hv;
}

// ---------------- QKV GEMM: 256x192 tile, BK=64, 12 waves of 64x64 --------
// C[m,n] = sum_k A[m,k]*Wc[n,k]; M=4096 N=3072 K=3072. Grid 256 (16m x 16n),
// 768 threads, waves 4x3 (wmr=wave&3 row-64, wnc=wave>>2 col-64 = one head).
// LDS dbuf: A 256x64 (32KB) + B 192x64 (24KB) = 56KB/buf. XOR swizzle
// col8^=(row&7) pre-applied on global source, applied on ds_read.
// Per K-tile: stage(nxt) | rd kk0 (8) | 16 MFMA | rd kk1 | 16 MFMA |
//             vmcnt(0) | barrier.  (stage post-barrier is race-free w/ dbuf)

__global__ __launch_bounds__(768, 3) void gemm_qkv_kernel(
    const bf16* __restrict__ A, const bf16* __restrict__ Bm,
    const float* __restrict__ b0, const float* __restrict__ b1,
    const float* __restrict__ b2, const float* __restrict__ g0,
    const float* __restrict__ g1, bf16* __restrict__ qn, bf16* __restrict__ kn,
    bf16* __restrict__ vt) {
  constexpr int K = 3072, NT = 48;
  __shared__ bf16 lds[2][3584 * 8];   // A chunks [0,2048), B chunks [2048,3584)
  const int tid  = threadIdx.x;
  const int wave = tid >> 6;
  const int lane = tid & 63;
  const int lm   = lane & 15;
  const int kg   = lane >> 4;
  const int wmr  = wave & 3;           // 0..3 row block (64 rows)
  const int wnc  = wave >> 2;          // 0..2 col block (64 cols = 1 head)
  // XCD swizzle: 256 blocks -> 32 consecutive logical per XCD (bijective)
  const int lid     = blockIdx.x;
  const int logical = ((lid & 7) << 5) | (lid >> 3);
  const int m0 = (logical >> 4) << 8;
  const int n0 = (logical & 15) * 192;

  auto stage = [&](int buf, int kt) {
#pragma unroll
    for (int j = 0; j < 5; ++j) {
      const int i = tid + j * 768;
      if (i < 3584) {
        if (i < 2048) {
          const int row  = i >> 3;
          const int col8 = (i & 7) ^ (row & 7);
          gload16(A + (size_t)(m0 + row) * K + kt + col8 * 8, &lds[buf][i * 8]);
        } else {
          const int i2   = i - 2048;
          const int row  = i2 >> 3;
          const int col8 = (i2 & 7) ^ (row & 7);
          gload16(Bm + (size_t)(n0 + row) * K + kt + col8 * 8, &lds[buf][i * 8]);
        }
      }
    }
  };

  auto rdA = [&](int buf, int r, int kk) -> bf16x8 {
    const int row = (wmr << 6) + (r << 4) + lm;   // 0..255
    return *(const bf16x8*)&lds[buf][(row * 8 + (((kk << 2) + kg) ^ (row & 7))) * 8];
  };
  auto rdB = [&](int buf, int c, int kk) -> bf16x8 {
    const int row = (wnc << 6) + (c << 4) + lm;   // 0..191
    return *(const bf16x8*)&lds[buf][(2048 * 8) + (row * 8 + (((kk << 2) + kg) ^ (row & 7))) * 8];
  };

  f32x4 acc[4][4] = {};

  stage(0, 0);
  S_WAITV(0);
  bar();

  for (int t = 0; t < NT; ++t) {
    const int cur = t & 1;
    if (t + 1 < NT) stage(cur ^ 1, (t + 1) << 6);

    bf16x8 a0[4], bq0[4];
#pragma unroll
    for (int r = 0; r < 4; ++r) a0[r] = rdA(cur, r, 0);
#pragma unroll
    for (int c = 0; c < 4; ++c) bq0[c] = rdB(cur, c, 0);
    __builtin_amdgcn_s_setprio(1);
#pragma unroll
    for (int r = 0; r < 4; ++r)
#pragma unroll
      for (int c = 0; c < 4; ++c)
        acc[r][c] = MFMA16(a0[r], bq0[c], acc[r][c], 0, 0, 0);
    __builtin_amdgcn_s_setprio(0);

    bf16x8 a1[4], bq1[4];
#pragma unroll
    for (int r = 0; r < 4; ++r) a1[r] = rdA(cur, r, 1);
#pragma unroll
    for (int c = 0; c < 4; ++c) bq1[c] = rdB(cur, c, 1);
    __builtin_amdgcn_s_setprio(1);
#pragma unroll
    for (int r = 0; r < 4; ++r)
#pragma unroll
      for (int c = 0; c < 4; ++c)
        acc[r][c] = MFMA16(a1[r], bq1[c], acc[r][c], 0, 0, 0);
    __builtin_amdgcn_s_setprio(0);

    S_WAITV(0);
    bar();
  }

  // ---- epilogue: one head per wave: bias + sfn (+ qk-norm) ----
  const int gcol = n0 + (wnc << 6);
  const int mat  = gcol >> 10;          // 0=q 1=k 2=v
  const int cb   = gcol & 1023;
  const int hh   = cb >> 6;
  const float* bias = (mat == 0) ? b0 : ((mat == 1) ? b1 : b2);
  float bvals[4];
#pragma unroll
  for (int j = 0; j < 4; ++j) bvals[j] = bias[cb + 16 * j + lm];

  if (mat < 2) {
    const float* gain = (mat == 0) ? g0 : g1;
    bf16* dst = (mat == 0) ? qn : kn;
    float gv[4];
#pragma unroll
    for (int j = 0; j < 4; ++j) gv[j] = gain[16 * j + lm];
#pragma unroll
    for (int r = 0; r < 4; ++r) {
      float y[4][4];
      float ss[4] = {0.f, 0.f, 0.f, 0.f};
#pragma unroll
      for (int j = 0; j < 4; ++j)
#pragma unroll
        for (int g = 0; g < 4; ++g) {
          float tq = sfn_f(acc[r][j][g] + bvals[j]);
          y[j][g] = tq;
          ss[g] += tq * tq;
        }
#pragma unroll
      for (int g = 0; g < 4; ++g) {
        float s = ss[g];
        s += __shfl_xor(s, 1);
        s += __shfl_xor(s, 2);
        s += __shfl_xor(s, 4);
        s += __shfl_xor(s, 8);
        ss[g] = 1.0f / sqrtf(s * (1.0f / 64.0f) + 1e-6f);
      }
      const int mbase = m0 + (wmr << 6) + 16 * r + 4 * kg;
      const int bb = mbase >> 11;
      const int ll = mbase & 2047;
#pragma unroll
      for (int g = 0; g < 4; ++g) {
        bf16* rowp = dst + ((size_t)(bb * 16 + hh) * 2048 + (ll + g)) * 64;
#pragma unroll
        for (int j = 0; j < 4; ++j)
          rowp[16 * j + lm] = (bf16)(y[j][g] * ss[g] * gv[j]);
      }
    }
  } else {
    // v: sfn only, store transposed [B,H,Dh,L]
#pragma unroll
    for (int r = 0; r < 4; ++r) {
      const int mbase = m0 + (wmr << 6) + 16 * r + 4 * kg;
      const int bb = mbase >> 11;
      const int ll = mbase & 2047;
#pragma unroll
      for (int j = 0; j < 4; ++j) {
        bf16x4 pk;
#pragma unroll
        for (int g = 0; g < 4; ++g)
          pk[g] = (bf16)sfn_f(acc[r][j][g] + bvals[j]);
        *(bf16x4*)(vt + ((size_t)(bb * 16 + hh) * 64 + 16 * j + lm) * 2048 + ll) = pk;
      }
    }
  }
}

// ---------------- O-projection GEMM (128x128, BK=32) ----------------

__global__ __launch_bounds__(256, 3) void gemm_o_kernel(
    const bf16* __restrict__ A, const bf16* __restrict__ Bm, int K,
    const float* __restrict__ b0, float* __restrict__ outf) {
  __shared__ bf16 sA[128 * 32];
  __shared__ bf16 sB[128 * 32];
  const int tid  = threadIdx.x;
  const int wave = tid >> 6;
  const int lane = tid & 63;
  const int lm   = lane & 15;
  const int kg   = lane >> 4;
  const int nbx = gridDim.x;
  const int lid = blockIdx.x + nbx * blockIdx.y;
  const int cpx = (nbx << 5) >> 3;
  const int logical = (lid & 7) * cpx + (lid >> 3);
  const int m0 = (logical / nbx) << 7;
  const int n0 = (logical % nbx) << 7;
  const int wm = (wave >> 1) << 6;
  const int wn = (wave & 1) << 6;

  f32x4 acc[4][4] = {};

  for (int kt = 0; kt < K; kt += 32) {
    __syncthreads();
#pragma unroll
    for (int j = 0; j < 2; ++j) {
      const int i   = wave * 128 + j * 64 + lane;
      const int row = i >> 2;
      const int kc  = (i & 3) << 3;
      gload16(A  + (size_t)(m0 + row) * K + kt + kc, sA + i * 8);
      gload16(Bm + (size_t)(n0 + row) * K + kt + kc, sB + i * 8);
    }
    __syncthreads();
    bf16x8 af[4], bfv[4];
#pragma unroll
    for (int r = 0; r < 4; ++r)
      af[r] = *(const bf16x8*)(sA + (wm + 16 * r + lm) * 32 + kg * 8);
#pragma unroll
    for (int c = 0; c < 4; ++c)
      bfv[c] = *(const bf16x8*)(sB + (wn + 16 * c + lm) * 32 + kg * 8);
#pragma unroll
    for (int r = 0; r < 4; ++r)
#pragma unroll
      for (int c = 0; c < 4; ++c)
        acc[r][c] = MFMA16(af[r], bfv[c], acc[r][c], 0, 0, 0);
  }

  float bvals[4];
#pragma unroll
  for (int c = 0; c < 4; ++c) bvals[c] = b0[n0 + wn + 16 * c + lm];
#pragma unroll
  for (int r = 0; r < 4; ++r) {
    const int mr = m0 + wm + 16 * r + 4 * kg;
#pragma unroll
    for (int c = 0; c < 4; ++c) {
      const int nc = n0 + wn + 16 * c + lm;
#pragma unroll
      for (int g = 0; g < 4; ++g)
        outf[(size_t)(mr + g) * 1024 + nc] = acc[r][c][g] + bvals[c];
    }
  }
}

// ---------------- attention ----------------
// grid (16, 32), 4 independent waves/block (no barriers), 32 q/wave.
// K/V read DIRECTLY from global (L2-resident per XCD after swizzle) into
// registers, double-buffered one tile ahead (named A/B buffers, rule #20).
// Fixed-max softmax (|s|<=8 after qk-norm); per-wave LDS P roundtrip only.

__global__ __launch_bounds__(256, 2) void attn_kernel(const bf16* __restrict__ qn,
                                                      const bf16* __restrict__ kn,
                                                      const bf16* __restrict__ vt,
                                                      bf16* __restrict__ ao) {
  __shared__ bf16 sP[4][16 * 72];
  const int tid  = threadIdx.x;
  const int wave = tid >> 6;
  const int lane = tid & 63;
  const int lm   = lane & 15;
  const int kg   = lane >> 4;
  const int lid     = blockIdx.x + (blockIdx.y << 4);
  const int logical = ((lid & 7) << 6) | (lid >> 3);
  const int qblk    = logical & 15;
  const int bh      = logical >> 4;
  const int q0      = (qblk << 7) + (wave << 5);
  const bf16* qb = qn + (size_t)bh * 2048 * 64;
  const bf16* kb = kn + (size_t)bh * 2048 * 64;
  const bf16* vb = vt + (size_t)bh * 64 * 2048;

  const float C1 = 0.125f * LOG2E;
  const float C2 = -8.0f * LOG2E;

  bf16x8 qf[2][2];
#pragma unroll
  for (int c = 0; c < 2; ++c)
#pragma unroll
    for (int dh = 0; dh < 2; ++dh)
      qf[c][dh] = *(const bf16x8*)(qb + (size_t)(q0 + 16 * c + lm) * 64 + dh * 32 + kg * 8);

  f32x4 o[4][2] = {};
  float lrun[2] = {0.f, 0.f};

  auto loadK = [&](bf16x8 (&ka)[4][2], int kt) {
#pragma unroll
    for (int rb = 0; rb < 4; ++rb)
#pragma unroll
      for (int dh = 0; dh < 2; ++dh)
        ka[rb][dh] = *(const bf16x8*)(kb + (size_t)(kt + 16 * rb + lm) * 64 + dh * 32 + kg * 8);
  };
  auto loadV = [&](bf16x8 (&va)[4][2], int kt) {
#pragma unroll
    for (int rbd = 0; rbd < 4; ++rbd)
#pragma unroll
      for (int kh = 0; kh < 2; ++kh)
        va[rbd][kh] = *(const bf16x8*)(vb + (size_t)(16 * rbd + lm) * 2048 + kt + kh * 32 + kg * 8);
  };

  auto tile = [&](const bf16x8 (&ka)[4][2], const bf16x8 (&va)[4][2]) {
    f32x4 s[4][2] = {};
    __builtin_amdgcn_s_setprio(1);
#pragma unroll
    for (int rb = 0; rb < 4; ++rb)
#pragma unroll
      for (int c = 0; c < 2; ++c)
#pragma unroll
        for (int dh = 0; dh < 2; ++dh)
          s[rb][c] = MFMA16(ka[rb][dh], qf[c][dh], s[rb][c], 0, 0, 0);
    __builtin_amdgcn_s_setprio(0);

    bf16x8 pb[2][2];
#pragma unroll
    for (int c = 0; c < 2; ++c) {
#pragma unroll
      for (int rb = 0; rb < 4; ++rb) {
        bf16x4 pk;
#pragma unroll
        for (int g = 0; g < 4; ++g) {
          float p = __builtin_amdgcn_exp2f(fmaf(s[rb][c][g], C1, C2));
          lrun[c] += p;
          pk[g] = (bf16)p;
        }
        *(bf16x4*)(&sP[wave][lm * 72 + 16 * rb + 4 * kg]) = pk;
      }
      asm volatile("s_waitcnt lgkmcnt(0)" ::: "memory");
#pragma unroll
      for (int kh = 0; kh < 2; ++kh)
        pb[c][kh] = *(const bf16x8*)(&sP[wave][lm * 72 + kh * 32 + kg * 8]);
    }

    __builtin_amdgcn_s_setprio(1);
#pragma unroll
    for (int rbd = 0; rbd < 4; ++rbd)
#pragma unroll
      for (int c = 0; c < 2; ++c)
#pragma unroll
        for (int kh = 0; kh < 2; ++kh)
          o[rbd][c] = MFMA16(va[rbd][kh], pb[c][kh], o[rbd][c], 0, 0, 0);
    __builtin_amdgcn_s_setprio(0);
  };

  bf16x8 kA[4][2], vA[4][2], kB[4][2], vB[4][2];
  loadK(kA, 0);
  loadV(vA, 0);
  for (int t = 0; t < 32; t += 2) {
    loadK(kB, (t + 1) << 6);
    loadV(vB, (t + 1) << 6);
    tile(kA, vA);
    if (t + 2 < 32) {
      loadK(kA, (t + 2) << 6);
      loadV(vA, (t + 2) << 6);
    }
    tile(kB, vB);
  }

  const int bb = bh >> 4;
  const int hh = bh & 15;
#pragma unroll
  for (int c = 0; c < 2; ++c) {
    float l = lrun[c];
    l += __shfl_xor(l, 16);
    l += __shfl_xor(l, 32);
    const float inv = 1.0f / l;
    const int q = q0 + 16 * c + lm;
    bf16* rowp = ao + (size_t)(bb * 2048 + q) * 1024 + hh * 64;
#pragma unroll
    for (int rbd = 0; rbd < 4; ++rbd) {
      bf16x4 pk;
#pragma unroll
      for (int g = 0; g < 4; ++g)
        pk[g] = (bf16)(o[rbd][c][g] * inv);
      *(bf16x4*)(rowp + 16 * rbd + 4 * kg) = pk;
    }
  }
}

// ---------------- launch ----------------

extern "C" void kernel_launch(void* const* d_in, const int* in_sizes, int n_in,
                              void* d_out, int out_size, void* d_ws, size_t ws_size,
                              hipStream_t stream) {
  const float* x  = (const float*)d_in[0];
  const float* Wq = (const float*)d_in[1];
  const float* bq = (const float*)d_in[2];
  const float* Wk = (const float*)d_in[3];
  const float* bk = (const float*)d_in[4];
  const float* Wv = (const float*)d_in[5];
  const float* bv = (const float*)d_in[6];
  const float* Wo = (const float*)d_in[7];
  const float* bo = (const float*)d_in[8];
  const float* gq = (const float*)d_in[9];
  const float* gk = (const float*)d_in[10];
  float* out = (float*)d_out;

  char* ws = (char*)d_ws;
  bf16* ax   = (bf16*)(ws);                    // [4096,3072]  25,165,824
  bf16* wc   = (bf16*)(ws + 25165824);         // [3072,3072]  18,874,368
  bf16* wob  = (bf16*)(ws + 44040192);         // [1024,1024]   2,097,152
  bf16* qn   = (bf16*)(ws + 46137344);         // [B,H,L,Dh]    8,388,608
  bf16* kn   = (bf16*)(ws + 54525952);         // [B,H,L,Dh]    8,388,608
  bf16* vt   = (bf16*)(ws + 62914560);         // [B,H,Dh,L]    8,388,608
  bf16* attn = (bf16*)(ws + 71303168);         // [4096,1024]   8,388,608

  prep_x_kernel<<<dim3(4096), dim3(256), 0, stream>>>(x, ax);
  prep_w_kernel<<<dim3(3072), dim3(256), 0, stream>>>(Wq, Wk, Wv, wc);
  prep_wo_kernel<<<dim3(1024), dim3(256), 0, stream>>>(Wo, wob);

  gemm_qkv_kernel<<<dim3(256), dim3(768), 0, stream>>>(
      ax, wc, bq, bk, bv, gq, gk, qn, kn, vt);

  attn_kernel<<<dim3(16, 32), dim3(256), 0, stream>>>(qn, kn, vt, attn);

  gemm_o_kernel<<<dim3(8, 32), dim3(256), 0, stream>>>(
      attn, wob, 1024, bo, out);
}

// Round 7
// 252.315 us; speedup vs baseline: 1.2105x; 1.2105x over previous
//
#include <hip/hip_runtime.h>
#include <math.h>

// SFNAttention on MI355X (gfx950).
// R7: qkv reverted to R5's proven 4-phase 256x192 kernel (86us).
//     attn rewritten: swapped QK^T on 32x32x16 MFMA -> P^T lane-local,
//     in-register softmax (fixed max), P->B-frag via pack + permlane32_swap
//     (no LDS P roundtrip), K/V LDS-staged (XOR both-sides) dbuf, 1 bar/tile.

typedef __bf16 bf16;
typedef bf16 bf16x4 __attribute__((ext_vector_type(4)));
typedef bf16 bf16x8 __attribute__((ext_vector_type(8)));
typedef float f32x4 __attribute__((ext_vector_type(4)));
typedef float f32x16 __attribute__((ext_vector_type(16)));
typedef unsigned int u32;
typedef u32 u32x4 __attribute__((ext_vector_type(4)));

#define LOG2E 1.4426950408889634f
#define MFMA16 __builtin_amdgcn_mfma_f32_16x16x32_bf16
#define MFMA32 __builtin_amdgcn_mfma_f32_32x32x16_bf16
#define S_WAITV(N) asm volatile("s_waitcnt vmcnt(" #N ")" ::: "memory")

__device__ __forceinline__ void bar() {
  asm volatile("" ::: "memory");
  __builtin_amdgcn_s_barrier();
  asm volatile("" ::: "memory");
}

__device__ __forceinline__ float sfn_f(float x) {
  return fminf(fmaxf(rintf(x + x), -8.0f), 8.0f) * 0.5f;
}

__device__ __forceinline__ void gload16(const bf16* g, bf16* l) {
  __builtin_amdgcn_global_load_lds((const __attribute__((address_space(1))) void*)g,
                                   (__attribute__((address_space(3))) void*)l, 16, 0, 0);
}

__device__ __forceinline__ u32 pkbf16(float a, float b) {
  unsigned short ua = __builtin_bit_cast(unsigned short, (bf16)a);
  unsigned short ub = __builtin_bit_cast(unsigned short, (bf16)b);
  return (u32)ua | ((u32)ub << 16);
}

// ---------------- prep kernels ----------------

__global__ __launch_bounds__(256) void prep_x_kernel(const float* __restrict__ x,
                                                     bf16* __restrict__ ax) {
  int idx = blockIdx.x * 256 + threadIdx.x;   // 1,048,576 = 4096*1024/4
  int m  = idx >> 8;
  int kc = (idx & 255) << 2;
  const float4 v = *(const float4*)(x + (size_t)m * 1024 + kc);
  bf16 h0 = (bf16)v.x, h1 = (bf16)v.y, h2 = (bf16)v.z, h3 = (bf16)v.w;
  bf16 l0 = (bf16)(v.x - (float)h0), l1 = (bf16)(v.y - (float)h1),
       l2 = (bf16)(v.z - (float)h2), l3 = (bf16)(v.w - (float)h3);
  bf16x4 hv = {h0, h1, h2, h3};
  bf16x4 lv = {l0, l1, l2, l3};
  bf16* p = ax + (size_t)m * 3072 + kc;
  *(bf16x4*)(p)        = hv;
  *(bf16x4*)(p + 1024) = lv;
  *(bf16x4*)(p + 2048) = hv;
}

__global__ __launch_bounds__(256) void prep_w_kernel(const float* __restrict__ Wq,
                                                     const float* __restrict__ Wk,
                                                     const float* __restrict__ Wv,
                                                     bf16* __restrict__ wc) {
  int idx = blockIdx.x * 256 + threadIdx.x;   // 786,432 = 3*1024*1024/4
  int mat = idx >> 18;
  int r   = idx & 262143;
  int n   = r >> 8;
  int kc  = (r & 255) << 2;
  const float* W = (mat == 0) ? Wq : ((mat == 1) ? Wk : Wv);
  const float4 v = *(const float4*)(W + (size_t)n * 1024 + kc);
  bf16 h0 = (bf16)v.x, h1 = (bf16)v.y, h2 = (bf16)v.z, h3 = (bf16)v.w;
  bf16 l0 = (bf16)(v.x - (float)h0), l1 = (bf16)(v.y - (float)h1),
       l2 = (bf16)(v.z - (float)h2), l3 = (bf16)(v.w - (float)h3);
  bf16x4 hv = {h0, h1, h2, h3};
  bf16x4 lv = {l0, l1, l2, l3};
  bf16* p = wc + (size_t)(mat * 1024 + n) * 3072 + kc;
  *(bf16x4*)(p)        = hv;
  *(bf16x4*)(p + 1024) = hv;
  *(bf16x4*)(p + 2048) = lv;
}

__global__ __launch_bounds__(256) void prep_wo_kernel(const float* __restrict__ Wo,
                                                      bf16* __restrict__ wob) {
  int idx = blockIdx.x * 256 + threadIdx.x;   // 262,144 = 1024*1024/4
  const float4 v = *(const float4*)(Wo + (size_t)idx * 4);
  bf16x4 hv = {(bf16)v.x, (bf16)v.y, (bf16)v.z, (bf16)v.w};
  *(bf16x4*)(wob + (size_t)idx * 4) = hv;
}

// ---------------- QKV GEMM: 256x192 tile, BK=64, grid 256 (R5, proven) -----

__global__ __launch_bounds__(512, 2) void gemm_qkv_kernel(
    const bf16* __restrict__ A, const bf16* __restrict__ Bm,
    const float* __restrict__ b0, const float* __restrict__ b1,
    const float* __restrict__ b2, const float* __restrict__ g0,
    const float* __restrict__ g1, bf16* __restrict__ qn, bf16* __restrict__ kn,
    bf16* __restrict__ vt) {
  constexpr int K = 3072, NT = 48;
  __shared__ bf16 lds[2][28672];   // A0@0  A1@8192  B0@16384 B1@20480 B2@24576
  const int tid  = threadIdx.x;
  const int wave = tid >> 6;
  const int lane = tid & 63;
  const int lm   = lane & 15;
  const int kg   = lane >> 4;
  const int lid     = blockIdx.x;
  const int logical = ((lid & 7) << 5) | (lid >> 3);
  const int m0 = (logical >> 4) << 8;
  const int n0 = (logical & 15) * 192;

  auto stageA = [&](int buf, int half, int kt) {
#pragma unroll
    for (int j = 0; j < 2; ++j) {
      const int c    = j * 512 + tid;
      const int row  = c >> 3;
      const int col8 = (c & 7) ^ (row & 7);
      gload16(A + (size_t)(m0 + half * 128 + row) * K + kt + col8 * 8,
              &lds[buf][half * 8192 + c * 8]);
    }
  };
  auto stageB = [&](int buf, int ch, int kt) {
    const int row  = tid >> 3;
    const int col8 = (tid & 7) ^ (row & 7);
    gload16(Bm + (size_t)(n0 + ch * 64 + row) * K + kt + col8 * 8,
            &lds[buf][16384 + ch * 4096 + tid * 8]);
  };

  const int sw    = lm & 7;
  const int arow  = (wave << 5) + lm;
  auto rdA = [&](int buf, int r, int kk) -> bf16x8 {
    const int row = arow + 16 * r;
    return *(const bf16x8*)&lds[buf][(row >> 7) * 8192 + (row & 127) * 64 +
                                     (((kk << 2) + kg) ^ sw) * 8];
  };
  auto rdB = [&](int buf, int c, int kk) -> bf16x8 {
    const int col = 16 * c + lm;
    return *(const bf16x8*)&lds[buf][16384 + (col >> 6) * 4096 + (col & 63) * 64 +
                                     (((kk << 2) + kg) ^ sw) * 8];
  };

  f32x4 acc[2][12] = {};

  stageA(0, 0, 0); stageA(0, 1, 0);
  stageB(0, 0, 0); stageB(0, 1, 0); stageB(0, 2, 0);
  stageA(1, 0, 64); stageA(1, 1, 64);
  S_WAITV(4);
  bar();

  for (int t = 0; t < NT; ++t) {
    const int cur = t & 1, nxt = cur ^ 1;
    const int kt1 = (t + 1) << 6, kt2 = (t + 2) << 6;
    bf16x8 a[2][2], bv[6];
#pragma unroll
    for (int r = 0; r < 2; ++r)
#pragma unroll
      for (int kk = 0; kk < 2; ++kk)
        a[r][kk] = rdA(cur, r, kk);
#pragma unroll
    for (int c = 0; c < 6; ++c) bv[c] = rdB(cur, c, 0);
    if (t + 1 < NT) stageB(nxt, 0, kt1);
    bar();
    __builtin_amdgcn_s_setprio(1);
#pragma unroll
    for (int r = 0; r < 2; ++r)
#pragma unroll
      for (int c = 0; c < 6; ++c)
        acc[r][c] = MFMA16(a[r][0], bv[c], acc[r][c], 0, 0, 0);
    __builtin_amdgcn_s_setprio(0);
    bar();
    bf16x8 bw[6];
#pragma unroll
    for (int c = 0; c < 6; ++c) bw[c] = rdB(cur, c + 6, 0);
    if (t + 1 < NT) { stageB(nxt, 1, kt1); stageB(nxt, 2, kt1); }
    bar();
    __builtin_amdgcn_s_setprio(1);
#pragma unroll
    for (int r = 0; r < 2; ++r)
#pragma unroll
      for (int c = 0; c < 6; ++c)
        acc[r][c + 6] = MFMA16(a[r][0], bw[c], acc[r][c + 6], 0, 0, 0);
    __builtin_amdgcn_s_setprio(0);
    bar();
    bf16x8 bx[6];
#pragma unroll
    for (int c = 0; c < 6; ++c) bx[c] = rdB(cur, c, 1);
    bar();
    __builtin_amdgcn_s_setprio(1);
#pragma unroll
    for (int r = 0; r < 2; ++r)
#pragma unroll
      for (int c = 0; c < 6; ++c)
        acc[r][c] = MFMA16(a[r][1], bx[c], acc[r][c], 0, 0, 0);
    __builtin_amdgcn_s_setprio(0);
    bar();
    bf16x8 by[6];
#pragma unroll
    for (int c = 0; c < 6; ++c) by[c] = rdB(cur, c + 6, 1);
    if (t + 2 < NT) {
      stageA(cur, 0, kt2); stageA(cur, 1, kt2);
      S_WAITV(4);
    } else {
      S_WAITV(0);
    }
    bar();
    __builtin_amdgcn_s_setprio(1);
#pragma unroll
    for (int r = 0; r < 2; ++r)
#pragma unroll
      for (int c = 0; c < 6; ++c)
        acc[r][c + 6] = MFMA16(a[r][1], by[c], acc[r][c + 6], 0, 0, 0);
    __builtin_amdgcn_s_setprio(0);
    bar();
  }

  // ---- epilogue: per head h (3 per wave): bias + sfn (+ qk-norm) ----
#pragma unroll
  for (int h = 0; h < 3; ++h) {
    const int gcol = n0 + (h << 6);
    const int mat  = gcol >> 10;
    const int cb   = gcol & 1023;
    const int hh   = cb >> 6;
    const float* bias = (mat == 0) ? b0 : ((mat == 1) ? b1 : b2);
    float bvals[4];
#pragma unroll
    for (int j = 0; j < 4; ++j) bvals[j] = bias[cb + 16 * j + lm];

    if (mat < 2) {
      const float* gain = (mat == 0) ? g0 : g1;
      bf16* dst = (mat == 0) ? qn : kn;
      float gv[4];
#pragma unroll
      for (int j = 0; j < 4; ++j) gv[j] = gain[16 * j + lm];
#pragma unroll
      for (int r = 0; r < 2; ++r) {
        float y[4][4];
        float ss[4] = {0.f, 0.f, 0.f, 0.f};
#pragma unroll
        for (int j = 0; j < 4; ++j)
#pragma unroll
          for (int g = 0; g < 4; ++g) {
            float tq = sfn_f(acc[r][4 * h + j][g] + bvals[j]);
            y[j][g] = tq;
            ss[g] += tq * tq;
          }
#pragma unroll
        for (int g = 0; g < 4; ++g) {
          float s = ss[g];
          s += __shfl_xor(s, 1);
          s += __shfl_xor(s, 2);
          s += __shfl_xor(s, 4);
          s += __shfl_xor(s, 8);
          ss[g] = 1.0f / sqrtf(s * (1.0f / 64.0f) + 1e-6f);
        }
        const int mbase = m0 + (wave << 5) + 16 * r + 4 * kg;
        const int bb = mbase >> 11;
        const int ll = mbase & 2047;
#pragma unroll
        for (int g = 0; g < 4; ++g) {
          bf16* rowp = dst + ((size_t)(bb * 16 + hh) * 2048 + (ll + g)) * 64;
#pragma unroll
          for (int j = 0; j < 4; ++j)
            rowp[16 * j + lm] = (bf16)(y[j][g] * ss[g] * gv[j]);
        }
      }
    } else {
#pragma unroll
      for (int r = 0; r < 2; ++r) {
        const int mbase = m0 + (wave << 5) + 16 * r + 4 * kg;
        const int bb = mbase >> 11;
        const int ll = mbase & 2047;
#pragma unroll
        for (int j = 0; j < 4; ++j) {
          bf16x4 pk;
#pragma unroll
          for (int g = 0; g < 4; ++g)
            pk[g] = (bf16)sfn_f(acc[r][4 * h + j][g] + bvals[j]);
          *(bf16x4*)(vt + ((size_t)(bb * 16 + hh) * 64 + 16 * j + lm) * 2048 + ll) = pk;
        }
      }
    }
  }
}

// ---------------- O-projection GEMM (128x128, BK=32) ----------------

__global__ __launch_bounds__(256, 3) void gemm_o_kernel(
    const bf16* __restrict__ A, const bf16* __restrict__ Bm, int K,
    const float* __restrict__ b0, float* __restrict__ outf) {
  __shared__ bf16 sA[128 * 32];
  __shared__ bf16 sB[128 * 32];
  const int tid  = threadIdx.x;
  const int wave = tid >> 6;
  const int lane = tid & 63;
  const int lm   = lane & 15;
  const int kg   = lane >> 4;
  const int nbx = gridDim.x;
  const int lid = blockIdx.x + nbx * blockIdx.y;
  const int cpx = (nbx << 5) >> 3;
  const int logical = (lid & 7) * cpx + (lid >> 3);
  const int m0 = (logical / nbx) << 7;
  const int n0 = (logical % nbx) << 7;
  const int wm = (wave >> 1) << 6;
  const int wn = (wave & 1) << 6;

  f32x4 acc[4][4] = {};

  for (int kt = 0; kt < K; kt += 32) {
    __syncthreads();
#pragma unroll
    for (int j = 0; j < 2; ++j) {
      const int i   = wave * 128 + j * 64 + lane;
      const int row = i >> 2;
      const int kc  = (i & 3) << 3;
      gload16(A  + (size_t)(m0 + row) * K + kt + kc, sA + i * 8);
      gload16(Bm + (size_t)(n0 + row) * K + kt + kc, sB + i * 8);
    }
    __syncthreads();
    bf16x8 af[4], bfv[4];
#pragma unroll
    for (int r = 0; r < 4; ++r)
      af[r] = *(const bf16x8*)(sA + (wm + 16 * r + lm) * 32 + kg * 8);
#pragma unroll
    for (int c = 0; c < 4; ++c)
      bfv[c] = *(const bf16x8*)(sB + (wn + 16 * c + lm) * 32 + kg * 8);
#pragma unroll
    for (int r = 0; r < 4; ++r)
#pragma unroll
      for (int c = 0; c < 4; ++c)
        acc[r][c] = MFMA16(af[r], bfv[c], acc[r][c], 0, 0, 0);
  }

  float bvals[4];
#pragma unroll
  for (int c = 0; c < 4; ++c) bvals[c] = b0[n0 + wn + 16 * c + lm];
#pragma unroll
  for (int r = 0; r < 4; ++r) {
    const int mr = m0 + wm + 16 * r + 4 * kg;
#pragma unroll
    for (int c = 0; c < 4; ++c) {
      const int nc = n0 + wn + 16 * c + lm;
#pragma unroll
      for (int g = 0; g < 4; ++g)
        outf[(size_t)(mr + g) * 1024 + nc] = acc[r][c][g] + bvals[c];
    }
  }
}

// ---------------- attention (swapped 32x32, in-register softmax) ----------
// grid (16, 32), 4 waves, 32 q/wave (q = lane&31). Per 64k tile (2 subtiles
// of 32k): S^T = sum_j mfma32(Kfrag_j, Qfrag_j)  (lane: q=lane&31,
// k=(reg&3)+8(reg>>2)+4hi). p=exp2(s*C1+C2) in-register; P^T -> PV B-frags
// via 8 pack + 4 v_permlane32_swap. PV: O^T[d][q] += mfma32(V^T-frag, pb).
// K,V LDS-staged (XOR both-sides), dbuf, 1 barrier + own-4-load drain/tile.

__global__ __launch_bounds__(256, 2) void attn_kernel(const bf16* __restrict__ qn,
                                                      const bf16* __restrict__ kn,
                                                      const bf16* __restrict__ vt,
                                                      bf16* __restrict__ ao) {
  __shared__ bf16 sK[2][64 * 64];
  __shared__ bf16 sV[2][64 * 64];
  const int tid  = threadIdx.x;
  const int wave = tid >> 6;
  const int lane = tid & 63;
  const int l31  = lane & 31;
  const int hi   = lane >> 5;
  const int lid     = blockIdx.x + (blockIdx.y << 4);
  const int logical = ((lid & 7) << 6) | (lid >> 3);
  const int qblk    = logical & 15;
  const int bh      = logical >> 4;
  const int q0      = (qblk << 7) + (wave << 5);
  const bf16* qb = qn + (size_t)bh * 2048 * 64;
  const bf16* kb = kn + (size_t)bh * 2048 * 64;
  const bf16* vb = vt + (size_t)bh * 64 * 2048;

  const float C1 = 0.125f * LOG2E;
  const float C2 = -8.0f * LOG2E;

  const int srow7 = lane >> 3;
  const int scl   = (lane & 7) ^ srow7;
  auto stageK = [&](int buf, int kt) {
#pragma unroll
    for (int j = 0; j < 2; ++j) {
      const int ci  = wave * 2 + j;
      const int row = ci * 8 + srow7;
      gload16(kb + (size_t)(kt + row) * 64 + scl * 8, &sK[buf][ci * 512]);
    }
  };
  auto stageV = [&](int buf, int kt) {
#pragma unroll
    for (int j = 0; j < 2; ++j) {
      const int ci  = wave * 2 + j;
      const int row = ci * 8 + srow7;       // row = d
      gload16(vb + (size_t)row * 2048 + kt + scl * 8, &sV[buf][ci * 512]);
    }
  };

  // Q frags (B-operand): lane q=l31, elements d = 16j + 8hi + e
  bf16x8 qf[4];
#pragma unroll
  for (int j = 0; j < 4; ++j)
    qf[j] = *(const bf16x8*)(qb + (size_t)(q0 + l31) * 64 + j * 16 + hi * 8);

  f32x16 o[2] = {};
  float lrun = 0.f;

  stageK(0, 0);
  stageV(0, 0);
  S_WAITV(0);
  bar();

  for (int t = 0; t < 32; ++t) {
    const int cur = t & 1;
    if (t < 31) { stageK(cur ^ 1, (t + 1) << 6); stageV(cur ^ 1, (t + 1) << 6); }

#pragma unroll
    for (int ks = 0; ks < 2; ++ks) {
      // K frags (A-operand): lane k-row = 32ks + l31, elements d = 16j+8hi+e
      const int krow = ks * 32 + l31;
      const int ksw  = krow & 7;
      bf16x8 kf[4];
#pragma unroll
      for (int j = 0; j < 4; ++j)
        kf[j] = *(const bf16x8*)(&sK[cur][krow * 64 + ((2 * j + hi) ^ ksw) * 8]);

      f32x16 s = {0.f, 0.f, 0.f, 0.f, 0.f, 0.f, 0.f, 0.f,
                  0.f, 0.f, 0.f, 0.f, 0.f, 0.f, 0.f, 0.f};
      __builtin_amdgcn_s_setprio(1);
#pragma unroll
      for (int j = 0; j < 4; ++j)
        s = MFMA32(kf[j], qf[j], s, 0, 0, 0);
      __builtin_amdgcn_s_setprio(0);

      // in-register softmax (fixed max): p[r], k=(r&3)+8(r>>2)+4hi
      float p[16];
#pragma unroll
      for (int r = 0; r < 16; ++r) {
        p[r] = __builtin_amdgcn_exp2f(fmaf(s[r], C1, C2));
        lrun += p[r];
      }
      // pack pairs -> words; swap lane-halves to build B-frags
      u32 w0 = pkbf16(p[0], p[1]),  w1 = pkbf16(p[2], p[3]);
      u32 w2 = pkbf16(p[4], p[5]),  w3 = pkbf16(p[6], p[7]);
      u32 w4 = pkbf16(p[8], p[9]),  w5 = pkbf16(p[10], p[11]);
      u32 w6 = pkbf16(p[12], p[13]), w7 = pkbf16(p[14], p[15]);
      asm volatile("v_permlane32_swap_b32 %0, %1" : "+v"(w0), "+v"(w2));
      asm volatile("v_permlane32_swap_b32 %0, %1" : "+v"(w1), "+v"(w3));
      asm volatile("v_permlane32_swap_b32 %0, %1" : "+v"(w4), "+v"(w6));
      asm volatile("v_permlane32_swap_b32 %0, %1" : "+v"(w5), "+v"(w7));
      const bf16x8 pb0 = __builtin_bit_cast(bf16x8, (u32x4){w0, w1, w2, w3});
      const bf16x8 pb1 = __builtin_bit_cast(bf16x8, (u32x4){w4, w5, w6, w7});

      // PV: O^T[d][q] += V^T-frag x pb ; d-row = 32rb + l31
#pragma unroll
      for (int rb = 0; rb < 2; ++rb) {
        const int vrow = rb * 32 + l31;
        const int vsw  = vrow & 7;
        const bf16x8 vf0 = *(const bf16x8*)(&sV[cur][vrow * 64 + ((4 * ks + hi) ^ vsw) * 8]);
        const bf16x8 vf1 = *(const bf16x8*)(&sV[cur][vrow * 64 + ((4 * ks + 2 + hi) ^ vsw) * 8]);
        __builtin_amdgcn_s_setprio(1);
        o[rb] = MFMA32(vf0, pb0, o[rb], 0, 0, 0);
        o[rb] = MFMA32(vf1, pb1, o[rb], 0, 0, 0);
        __builtin_amdgcn_s_setprio(0);
      }
    }

    S_WAITV(0);     // own 4 staged loads, issued ~whole tile ago
    bar();
  }

  lrun += __shfl_xor(lrun, 32);
  const float inv = 1.0f / lrun;
  const int bb = bh >> 4;
  const int hh = bh & 15;
  bf16* rowp = ao + (size_t)(bb * 2048 + q0 + l31) * 1024 + hh * 64;
#pragma unroll
  for (int rb = 0; rb < 2; ++rb)
#pragma unroll
    for (int r4 = 0; r4 < 4; ++r4) {
      bf16x4 pk;
#pragma unroll
      for (int g = 0; g < 4; ++g)
        pk[g] = (bf16)(o[rb][r4 * 4 + g] * inv);
      *(bf16x4*)(rowp + rb * 32 + r4 * 8 + hi * 4) = pk;
    }
}

// ---------------- launch ----------------

extern "C" void kernel_launch(void* const* d_in, const int* in_sizes, int n_in,
                              void* d_out, int out_size, void* d_ws, size_t ws_size,
                              hipStream_t stream) {
  const float* x  = (const float*)d_in[0];
  const float* Wq = (const float*)d_in[1];
  const float* bq = (const float*)d_in[2];
  const float* Wk = (const float*)d_in[3];
  const float* bk = (const float*)d_in[4];
  const float* Wv = (const float*)d_in[5];
  const float* bv = (const float*)d_in[6];
  const float* Wo = (const float*)d_in[7];
  const float* bo = (const float*)d_in[8];
  const float* gq = (const float*)d_in[9];
  const float* gk = (const float*)d_in[10];
  float* out = (float*)d_out;

  char* ws = (char*)d_ws;
  bf16* ax   = (bf16*)(ws);                    // [4096,3072]  25,165,824
  bf16* wc   = (bf16*)(ws + 25165824);         // [3072,3072]  18,874,368
  bf16* wob  = (bf16*)(ws + 44040192);         // [1024,1024]   2,097,152
  bf16* qn   = (bf16*)(ws + 46137344);         // [B,H,L,Dh]    8,388,608
  bf16* kn   = (bf16*)(ws + 54525952);         // [B,H,L,Dh]    8,388,608
  bf16* vt   = (bf16*)(ws + 62914560);         // [B,H,Dh,L]    8,388,608
  bf16* attn = (bf16*)(ws + 71303168);         // [4096,1024]   8,388,608

  prep_x_kernel<<<dim3(4096), dim3(256), 0, stream>>>(x, ax);
  prep_w_kernel<<<dim3(3072), dim3(256), 0, stream>>>(Wq, Wk, Wv, wc);
  prep_wo_kernel<<<dim3(1024), dim3(256), 0, stream>>>(Wo, wob);

  gemm_qkv_kernel<<<dim3(256), dim3(512), 0, stream>>>(
      ax, wc, bq, bk, bv, gq, gk, qn, kn, vt);

  attn_kernel<<<dim3(16, 32), dim3(256), 0, stream>>>(qn, kn, vt, attn);

  gemm_o_kernel<<<dim3(8, 32), dim3(256), 0, stream>>>(
      attn, wob, 1024, bo, out);
}

// Round 8
// 245.397 us; speedup vs baseline: 1.2447x; 1.0282x over previous
//
#include <hip/hip_runtime.h>
#include <math.h>

// SFNAttention on MI355X (gfx950).
// R8: qkv -> wave grid 4x2 (wave tile 64x96) to cut LDS read traffic
//     224KB->160KB/tile (LDS-pipe-bound fix); split-head qk-norm via
//     per-block partial-ss LDS exchange. gemm_o -> counted-vmcnt 2-phase
//     128x128/BK=64 structure (replaces drain-every-tile loop).
//     attn (R7 swapped-32x32 in-register softmax) unchanged.

typedef __bf16 bf16;
typedef bf16 bf16x4 __attribute__((ext_vector_type(4)));
typedef bf16 bf16x8 __attribute__((ext_vector_type(8)));
typedef float f32x4 __attribute__((ext_vector_type(4)));
typedef float f32x16 __attribute__((ext_vector_type(16)));
typedef unsigned int u32;
typedef u32 u32x4 __attribute__((ext_vector_type(4)));

#define LOG2E 1.4426950408889634f
#define MFMA16 __builtin_amdgcn_mfma_f32_16x16x32_bf16
#define MFMA32 __builtin_amdgcn_mfma_f32_32x32x16_bf16
#define S_WAITV(N) asm volatile("s_waitcnt vmcnt(" #N ")" ::: "memory")

__device__ __forceinline__ void bar() {
  asm volatile("" ::: "memory");
  __builtin_amdgcn_s_barrier();
  asm volatile("" ::: "memory");
}

__device__ __forceinline__ float sfn_f(float x) {
  return fminf(fmaxf(rintf(x + x), -8.0f), 8.0f) * 0.5f;
}

__device__ __forceinline__ void gload16(const bf16* g, bf16* l) {
  __builtin_amdgcn_global_load_lds((const __attribute__((address_space(1))) void*)g,
                                   (__attribute__((address_space(3))) void*)l, 16, 0, 0);
}

__device__ __forceinline__ u32 pkbf16(float a, float b) {
  unsigned short ua = __builtin_bit_cast(unsigned short, (bf16)a);
  unsigned short ub = __builtin_bit_cast(unsigned short, (bf16)b);
  return (u32)ua | ((u32)ub << 16);
}

// ---------------- prep kernels ----------------

__global__ __launch_bounds__(256) void prep_x_kernel(const float* __restrict__ x,
                                                     bf16* __restrict__ ax) {
  int idx = blockIdx.x * 256 + threadIdx.x;
  int m  = idx >> 8;
  int kc = (idx & 255) << 2;
  const float4 v = *(const float4*)(x + (size_t)m * 1024 + kc);
  bf16 h0 = (bf16)v.x, h1 = (bf16)v.y, h2 = (bf16)v.z, h3 = (bf16)v.w;
  bf16 l0 = (bf16)(v.x - (float)h0), l1 = (bf16)(v.y - (float)h1),
       l2 = (bf16)(v.z - (float)h2), l3 = (bf16)(v.w - (float)h3);
  bf16x4 hv = {h0, h1, h2, h3};
  bf16x4 lv = {l0, l1, l2, l3};
  bf16* p = ax + (size_t)m * 3072 + kc;
  *(bf16x4*)(p)        = hv;
  *(bf16x4*)(p + 1024) = lv;
  *(bf16x4*)(p + 2048) = hv;
}

__global__ __launch_bounds__(256) void prep_w_kernel(const float* __restrict__ Wq,
                                                     const float* __restrict__ Wk,
                                                     const float* __restrict__ Wv,
                                                     bf16* __restrict__ wc) {
  int idx = blockIdx.x * 256 + threadIdx.x;
  int mat = idx >> 18;
  int r   = idx & 262143;
  int n   = r >> 8;
  int kc  = (r & 255) << 2;
  const float* W = (mat == 0) ? Wq : ((mat == 1) ? Wk : Wv);
  const float4 v = *(const float4*)(W + (size_t)n * 1024 + kc);
  bf16 h0 = (bf16)v.x, h1 = (bf16)v.y, h2 = (bf16)v.z, h3 = (bf16)v.w;
  bf16 l0 = (bf16)(v.x - (float)h0), l1 = (bf16)(v.y - (float)h1),
       l2 = (bf16)(v.z - (float)h2), l3 = (bf16)(v.w - (float)h3);
  bf16x4 hv = {h0, h1, h2, h3};
  bf16x4 lv = {l0, l1, l2, l3};
  bf16* p = wc + (size_t)(mat * 1024 + n) * 3072 + kc;
  *(bf16x4*)(p)        = hv;
  *(bf16x4*)(p + 1024) = hv;
  *(bf16x4*)(p + 2048) = lv;
}

__global__ __launch_bounds__(256) void prep_wo_kernel(const float* __restrict__ Wo,
                                                      bf16* __restrict__ wob) {
  int idx = blockIdx.x * 256 + threadIdx.x;
  const float4 v = *(const float4*)(Wo + (size_t)idx * 4);
  bf16x4 hv = {(bf16)v.x, (bf16)v.y, (bf16)v.z, (bf16)v.w};
  *(bf16x4*)(wob + (size_t)idx * 4) = hv;
}

// ---------------- QKV GEMM: 256x192 tile, BK=64, waves 4x2 ----------------
// Wave (wr=wave&3, wc=wave>>2): rows 64*wr..+63, cols 96*wc..+95 -> acc[4][6].
// LDS traffic/tile = A*2 + B*4 = 160KB (was 224KB at 8x1). Staging schedule
// and per-element accumulation order identical to R5 (counted vmcnt(4)).
// Epilogue: full heads normed in-wave (bit-identical tree); split middle head
// via partial-ss exchange through LDS (one extra barrier).

__global__ __launch_bounds__(512, 2) void gemm_qkv_kernel(
    const bf16* __restrict__ A, const bf16* __restrict__ Bm,
    const float* __restrict__ b0, const float* __restrict__ b1,
    const float* __restrict__ b2, const float* __restrict__ g0,
    const float* __restrict__ g1, bf16* __restrict__ qn, bf16* __restrict__ kn,
    bf16* __restrict__ vt) {
  constexpr int K = 3072, NT = 48;
  __shared__ bf16 lds[2][28672];   // A0@0  A1@8192  B0@16384 B1@20480 B2@24576
  const int tid  = threadIdx.x;
  const int wave = tid >> 6;
  const int lane = tid & 63;
  const int lm   = lane & 15;
  const int kg   = lane >> 4;
  const int wr   = wave & 3;       // row block (64 rows)
  const int wc   = wave >> 2;      // col block (96 cols)
  const int lid     = blockIdx.x;
  const int logical = ((lid & 7) << 5) | (lid >> 3);
  const int m0 = (logical >> 4) << 8;
  const int n0 = (logical & 15) * 192;

  auto stageA = [&](int buf, int half, int kt) {
#pragma unroll
    for (int j = 0; j < 2; ++j) {
      const int c    = j * 512 + tid;
      const int row  = c >> 3;
      const int col8 = (c & 7) ^ (row & 7);
      gload16(A + (size_t)(m0 + half * 128 + row) * K + kt + col8 * 8,
              &lds[buf][half * 8192 + c * 8]);
    }
  };
  auto stageB = [&](int buf, int ch, int kt) {
    const int row  = tid >> 3;
    const int col8 = (tid & 7) ^ (row & 7);
    gload16(Bm + (size_t)(n0 + ch * 64 + row) * K + kt + col8 * 8,
            &lds[buf][16384 + ch * 4096 + tid * 8]);
  };

  auto rdA = [&](int buf, int r, int kk) -> bf16x8 {
    const int row = (wr << 6) + (r << 4) + lm;        // 0..255
    return *(const bf16x8*)&lds[buf][(row >> 7) * 8192 + (row & 127) * 64 +
                                     (((kk << 2) + kg) ^ (row & 7)) * 8];
  };
  auto rdB = [&](int buf, int c, int kk) -> bf16x8 {
    const int col = wc * 96 + (c << 4) + lm;          // 0..191
    return *(const bf16x8*)&lds[buf][16384 + (col >> 6) * 4096 + (col & 63) * 64 +
                                     (((kk << 2) + kg) ^ (col & 7)) * 8];
  };

  f32x4 acc[4][6] = {};

  stageA(0, 0, 0); stageA(0, 1, 0);
  stageB(0, 0, 0); stageB(0, 1, 0); stageB(0, 2, 0);
  stageA(1, 0, 64); stageA(1, 1, 64);
  S_WAITV(4);
  bar();

  for (int t = 0; t < NT; ++t) {
    const int cur = t & 1, nxt = cur ^ 1;
    const int kt1 = (t + 1) << 6, kt2 = (t + 2) << 6;
    bf16x8 a0[4], a1[4], bA[3], bB[3], bC[3], bD[3];
    // ---- P0: rdA kk0 + rdB kk0 c0-2 ; stage B0(t+1)
#pragma unroll
    for (int r = 0; r < 4; ++r) a0[r] = rdA(cur, r, 0);
#pragma unroll
    for (int c = 0; c < 3; ++c) bA[c] = rdB(cur, c, 0);
    if (t + 1 < NT) stageB(nxt, 0, kt1);
    bar();
    __builtin_amdgcn_s_setprio(1);
#pragma unroll
    for (int r = 0; r < 4; ++r)
#pragma unroll
      for (int c = 0; c < 3; ++c)
        acc[r][c] = MFMA16(a0[r], bA[c], acc[r][c], 0, 0, 0);
    __builtin_amdgcn_s_setprio(0);
    bar();
    // ---- P1: rdB kk0 c3-5 ; stage B1,B2(t+1)
#pragma unroll
    for (int c = 0; c < 3; ++c) bB[c] = rdB(cur, c + 3, 0);
    if (t + 1 < NT) { stageB(nxt, 1, kt1); stageB(nxt, 2, kt1); }
    bar();
    __builtin_amdgcn_s_setprio(1);
#pragma unroll
    for (int r = 0; r < 4; ++r)
#pragma unroll
      for (int c = 0; c < 3; ++c)
        acc[r][c + 3] = MFMA16(a0[r], bB[c], acc[r][c + 3], 0, 0, 0);
    __builtin_amdgcn_s_setprio(0);
    bar();
    // ---- P2: rdA kk1 + rdB kk1 c0-2
#pragma unroll
    for (int r = 0; r < 4; ++r) a1[r] = rdA(cur, r, 1);
#pragma unroll
    for (int c = 0; c < 3; ++c) bC[c] = rdB(cur, c, 1);
    bar();
    __builtin_amdgcn_s_setprio(1);
#pragma unroll
    for (int r = 0; r < 4; ++r)
#pragma unroll
      for (int c = 0; c < 3; ++c)
        acc[r][c] = MFMA16(a1[r], bC[c], acc[r][c], 0, 0, 0);
    __builtin_amdgcn_s_setprio(0);
    bar();
    // ---- P3: rdB kk1 c3-5 ; stage A(t+2) into cur ; counted wait
#pragma unroll
    for (int c = 0; c < 3; ++c) bD[c] = rdB(cur, c + 3, 1);
    if (t + 2 < NT) {
      stageA(cur, 0, kt2); stageA(cur, 1, kt2);
      S_WAITV(4);
    } else {
      S_WAITV(0);
    }
    bar();
    __builtin_amdgcn_s_setprio(1);
#pragma unroll
    for (int r = 0; r < 4; ++r)
#pragma unroll
      for (int c = 0; c < 3; ++c)
        acc[r][c + 3] = MFMA16(a1[r], bD[c], acc[r][c + 3], 0, 0, 0);
    __builtin_amdgcn_s_setprio(0);
    bar();
  }

  // ---- epilogue ----
  // Wave covers: full head (frags fc0..fc0+3) + half of the middle head
  // (frags hc0,hc0+1; col offset hoff within that head).
  const int fc0   = wc ? 2 : 0;
  const int fgcol = n0 + (wc ? 128 : 0);
  const int hc0   = wc ? 0 : 4;
  const int hoff  = wc ? 32 : 0;
  const int hgcol = n0 + 64;

  const int fmat = fgcol >> 10, fhh = (fgcol & 1023) >> 6;
  const int hmat = hgcol >> 10, hhh = (hgcol & 1023) >> 6;
  const float* fbias = (fmat == 0) ? b0 : ((fmat == 1) ? b1 : b2);
  const float* hbias = (hmat == 0) ? b0 : ((hmat == 1) ? b1 : b2);

  float fb[4], hb[2];
#pragma unroll
  for (int c = 0; c < 4; ++c) fb[c] = fbias[(fgcol & 1023) + 16 * c + lm];
#pragma unroll
  for (int c = 0; c < 2; ++c) hb[c] = hbias[(hgcol & 1023) + hoff + 16 * c + lm];

  // partial sum-of-squares per local row lr = 16r + 4kg + g
  float ffs[4][4], phs[4][4];
#pragma unroll
  for (int r = 0; r < 4; ++r)
#pragma unroll
    for (int g = 0; g < 4; ++g) {
      float sf = 0.f, sh = 0.f;
#pragma unroll
      for (int c = 0; c < 4; ++c) {
        float t = sfn_f(acc[r][fc0 + c][g] + fb[c]);
        sf += t * t;
      }
#pragma unroll
      for (int c = 0; c < 2; ++c) {
        float t = sfn_f(acc[r][hc0 + c][g] + hb[c]);
        sh += t * t;
      }
      ffs[r][g] = sf;
      phs[r][g] = sh;
    }
#pragma unroll
  for (int r = 0; r < 4; ++r)
#pragma unroll
    for (int g = 0; g < 4; ++g)
#pragma unroll
      for (int d = 1; d < 16; d <<= 1) {
        ffs[r][g] += __shfl_xor(ffs[r][g], d);
        phs[r][g] += __shfl_xor(phs[r][g], d);
      }

  // exchange half-head partials with partner wave (wr, wc^1)
  float* sSS = (float*)&lds[0][0];
  if (lm == 0) {
#pragma unroll
    for (int r = 0; r < 4; ++r)
#pragma unroll
      for (int g = 0; g < 4; ++g)
        sSS[((wr << 1) | wc) * 64 + 16 * r + 4 * kg + g] = phs[r][g];
  }
  bar();
  float pot[4][4];
#pragma unroll
  for (int r = 0; r < 4; ++r)
#pragma unroll
    for (int g = 0; g < 4; ++g)
      pot[r][g] = sSS[((wr << 1) | (wc ^ 1)) * 64 + 16 * r + 4 * kg + g];

  // ---- FULL head ----
  if (fmat < 2) {
    const float* gain = (fmat == 0) ? g0 : g1;
    bf16* dst = (fmat == 0) ? qn : kn;
    float gv[4];
#pragma unroll
    for (int c = 0; c < 4; ++c) gv[c] = gain[16 * c + lm];
#pragma unroll
    for (int r = 0; r < 4; ++r) {
      const int mbase = m0 + (wr << 6) + 16 * r + 4 * kg;
      const int bb = mbase >> 11;
      const int ll = mbase & 2047;
#pragma unroll
      for (int g = 0; g < 4; ++g) {
        const float inv = 1.0f / sqrtf(ffs[r][g] * (1.0f / 64.0f) + 1e-6f);
        bf16* rowp = dst + ((size_t)(bb * 16 + fhh) * 2048 + (ll + g)) * 64;
#pragma unroll
        for (int c = 0; c < 4; ++c)
          rowp[16 * c + lm] = (bf16)(sfn_f(acc[r][fc0 + c][g] + fb[c]) * inv * gv[c]);
      }
    }
  } else {
#pragma unroll
    for (int r = 0; r < 4; ++r) {
      const int mbase = m0 + (wr << 6) + 16 * r + 4 * kg;
      const int bb = mbase >> 11;
      const int ll = mbase & 2047;
#pragma unroll
      for (int c = 0; c < 4; ++c) {
        bf16x4 pk;
#pragma unroll
        for (int g = 0; g < 4; ++g)
          pk[g] = (bf16)sfn_f(acc[r][fc0 + c][g] + fb[c]);
        *(bf16x4*)(vt + ((size_t)(bb * 16 + fhh) * 64 + 16 * c + lm) * 2048 + ll) = pk;
      }
    }
  }

  // ---- HALF (middle) head ----
  if (hmat < 2) {
    const float* gain = (hmat == 0) ? g0 : g1;
    bf16* dst = (hmat == 0) ? qn : kn;
    float gv[2];
#pragma unroll
    for (int c = 0; c < 2; ++c) gv[c] = gain[hoff + 16 * c + lm];
#pragma unroll
    for (int r = 0; r < 4; ++r) {
      const int mbase = m0 + (wr << 6) + 16 * r + 4 * kg;
      const int bb = mbase >> 11;
      const int ll = mbase & 2047;
#pragma unroll
      for (int g = 0; g < 4; ++g) {
        const float ss  = phs[r][g] + pot[r][g];
        const float inv = 1.0f / sqrtf(ss * (1.0f / 64.0f) + 1e-6f);
        bf16* rowp = dst + ((size_t)(bb * 16 + hhh) * 2048 + (ll + g)) * 64;
#pragma unroll
        for (int c = 0; c < 2; ++c)
          rowp[hoff + 16 * c + lm] = (bf16)(sfn_f(acc[r][hc0 + c][g] + hb[c]) * inv * gv[c]);
      }
    }
  } else {
#pragma unroll
    for (int r = 0; r < 4; ++r) {
      const int mbase = m0 + (wr << 6) + 16 * r + 4 * kg;
      const int bb = mbase >> 11;
      const int ll = mbase & 2047;
#pragma unroll
      for (int c = 0; c < 2; ++c) {
        bf16x4 pk;
#pragma unroll
        for (int g = 0; g < 4; ++g)
          pk[g] = (bf16)sfn_f(acc[r][hc0 + c][g] + hb[c]);
        *(bf16x4*)(vt + ((size_t)(bb * 16 + hhh) * 64 + hoff + 16 * c + lm) * 2048 + ll) = pk;
      }
    }
  }
}

// ---------------- O-projection GEMM: 128x128, BK=64, counted vmcnt --------
// M=4096 N=1024 K=1024; grid 256 (32m x 8n), 4 waves (2x2), acc[4][4].
// LDS 64KB dbuf -> 2 blocks/CU. A(t+2) staged into freed half of cur buf.

__global__ __launch_bounds__(256, 2) void gemm_o_kernel(
    const bf16* __restrict__ A, const bf16* __restrict__ Bm,
    const float* __restrict__ b0, float* __restrict__ outf) {
  constexpr int K = 1024, NT = 16;
  __shared__ bf16 lds[2][16384];    // A@0 (128x64), B@8192
  const int tid  = threadIdx.x;
  const int wave = tid >> 6;
  const int lane = tid & 63;
  const int lm   = lane & 15;
  const int kg   = lane >> 4;
  const int wr   = wave & 1;
  const int wcb  = wave >> 1;
  const int lid     = blockIdx.x;
  const int logical = ((lid & 7) << 5) | (lid >> 3);
  const int m0 = (logical >> 3) << 7;    // 32 m-tiles
  const int n0 = (logical & 7) << 7;     // 8 n-tiles

  auto stageA = [&](int buf, int kt) {
#pragma unroll
    for (int j = 0; j < 4; ++j) {
      const int i    = j * 256 + tid;    // 0..1023
      const int row  = i >> 3;
      const int col8 = (i & 7) ^ (row & 7);
      gload16(A + (size_t)(m0 + row) * K + kt + col8 * 8, &lds[buf][i * 8]);
    }
  };
  auto stageB = [&](int buf, int kt) {
#pragma unroll
    for (int j = 0; j < 4; ++j) {
      const int i    = j * 256 + tid;
      const int row  = i >> 3;
      const int col8 = (i & 7) ^ (row & 7);
      gload16(Bm + (size_t)(n0 + row) * K + kt + col8 * 8, &lds[buf][8192 + i * 8]);
    }
  };
  auto rdA = [&](int buf, int r, int kk) -> bf16x8 {
    const int row = (wr << 6) + (r << 4) + lm;
    return *(const bf16x8*)&lds[buf][row * 64 + (((kk << 2) + kg) ^ (row & 7)) * 8];
  };
  auto rdB = [&](int buf, int c, int kk) -> bf16x8 {
    const int row = (wcb << 6) + (c << 4) + lm;
    return *(const bf16x8*)&lds[buf][8192 + row * 64 + (((kk << 2) + kg) ^ (row & 7)) * 8];
  };

  f32x4 acc[4][4] = {};

  stageA(0, 0); stageB(0, 0); stageA(1, 64);
  S_WAITV(4);
  bar();

  for (int t = 0; t < NT; ++t) {
    const int cur = t & 1, nxt = cur ^ 1;
    bf16x8 a0[4], a1[4], bq0[4], bq1[4];
    // ---- P0: rd all A + B kk0 ; stage B(t+1)
#pragma unroll
    for (int r = 0; r < 4; ++r) { a0[r] = rdA(cur, r, 0); a1[r] = rdA(cur, r, 1); }
#pragma unroll
    for (int c = 0; c < 4; ++c) bq0[c] = rdB(cur, c, 0);
    if (t + 1 < NT) stageB(nxt, (t + 1) << 6);
    bar();
    __builtin_amdgcn_s_setprio(1);
#pragma unroll
    for (int r = 0; r < 4; ++r)
#pragma unroll
      for (int c = 0; c < 4; ++c)
        acc[r][c] = MFMA16(a0[r], bq0[c], acc[r][c], 0, 0, 0);
    __builtin_amdgcn_s_setprio(0);
    bar();
    // ---- P1: rd B kk1 ; stage A(t+2) into cur ; counted wait
#pragma unroll
    for (int c = 0; c < 4; ++c) bq1[c] = rdB(cur, c, 1);
    if (t + 2 < NT) {
      stageA(cur, (t + 2) << 6);
      S_WAITV(4);
    } else {
      S_WAITV(0);
    }
    bar();
    __builtin_amdgcn_s_setprio(1);
#pragma unroll
    for (int r = 0; r < 4; ++r)
#pragma unroll
      for (int c = 0; c < 4; ++c)
        acc[r][c] = MFMA16(a1[r], bq1[c], acc[r][c], 0, 0, 0);
    __builtin_amdgcn_s_setprio(0);
    bar();
  }

  float bvals[4];
#pragma unroll
  for (int c = 0; c < 4; ++c) bvals[c] = b0[n0 + (wcb << 6) + 16 * c + lm];
#pragma unroll
  for (int r = 0; r < 4; ++r) {
    const int mr = m0 + (wr << 6) + 16 * r + 4 * kg;
#pragma unroll
    for (int c = 0; c < 4; ++c) {
      const int nc = n0 + (wcb << 6) + 16 * c + lm;
#pragma unroll
      for (int g = 0; g < 4; ++g)
        outf[(size_t)(mr + g) * 1024 + nc] = acc[r][c][g] + bvals[c];
    }
  }
}

// ---------------- attention (R7: swapped 32x32, in-register softmax) -------

__global__ __launch_bounds__(256, 2) void attn_kernel(const bf16* __restrict__ qn,
                                                      const bf16* __restrict__ kn,
                                                      const bf16* __restrict__ vt,
                                                      bf16* __restrict__ ao) {
  __shared__ bf16 sK[2][64 * 64];
  __shared__ bf16 sV[2][64 * 64];
  const int tid  = threadIdx.x;
  const int wave = tid >> 6;
  const int lane = tid & 63;
  const int l31  = lane & 31;
  const int hi   = lane >> 5;
  const int lid     = blockIdx.x + (blockIdx.y << 4);
  const int logical = ((lid & 7) << 6) | (lid >> 3);
  const int qblk    = logical & 15;
  const int bh      = logical >> 4;
  const int q0      = (qblk << 7) + (wave << 5);
  const bf16* qb = qn + (size_t)bh * 2048 * 64;
  const bf16* kb = kn + (size_t)bh * 2048 * 64;
  const bf16* vb = vt + (size_t)bh * 64 * 2048;

  const float C1 = 0.125f * LOG2E;
  const float C2 = -8.0f * LOG2E;

  const int srow7 = lane >> 3;
  const int scl   = (lane & 7) ^ srow7;
  auto stageK = [&](int buf, int kt) {
#pragma unroll
    for (int j = 0; j < 2; ++j) {
      const int ci  = wave * 2 + j;
      const int row = ci * 8 + srow7;
      gload16(kb + (size_t)(kt + row) * 64 + scl * 8, &sK[buf][ci * 512]);
    }
  };
  auto stageV = [&](int buf, int kt) {
#pragma unroll
    for (int j = 0; j < 2; ++j) {
      const int ci  = wave * 2 + j;
      const int row = ci * 8 + srow7;
      gload16(vb + (size_t)row * 2048 + kt + scl * 8, &sV[buf][ci * 512]);
    }
  };

  bf16x8 qf[4];
#pragma unroll
  for (int j = 0; j < 4; ++j)
    qf[j] = *(const bf16x8*)(qb + (size_t)(q0 + l31) * 64 + j * 16 + hi * 8);

  f32x16 o[2] = {};
  float lrun = 0.f;

  stageK(0, 0);
  stageV(0, 0);
  S_WAITV(0);
  bar();

  for (int t = 0; t < 32; ++t) {
    const int cur = t & 1;
    if (t < 31) { stageK(cur ^ 1, (t + 1) << 6); stageV(cur ^ 1, (t + 1) << 6); }

#pragma unroll
    for (int ks = 0; ks < 2; ++ks) {
      const int krow = ks * 32 + l31;
      const int ksw  = krow & 7;
      bf16x8 kf[4];
#pragma unroll
      for (int j = 0; j < 4; ++j)
        kf[j] = *(const bf16x8*)(&sK[cur][krow * 64 + ((2 * j + hi) ^ ksw) * 8]);

      f32x16 s = {0.f, 0.f, 0.f, 0.f, 0.f, 0.f, 0.f, 0.f,
                  0.f, 0.f, 0.f, 0.f, 0.f, 0.f, 0.f, 0.f};
      __builtin_amdgcn_s_setprio(1);
#pragma unroll
      for (int j = 0; j < 4; ++j)
        s = MFMA32(kf[j], qf[j], s, 0, 0, 0);
      __builtin_amdgcn_s_setprio(0);

      float p[16];
#pragma unroll
      for (int r = 0; r < 16; ++r) {
        p[r] = __builtin_amdgcn_exp2f(fmaf(s[r], C1, C2));
        lrun += p[r];
      }
      u32 w0 = pkbf16(p[0], p[1]),  w1 = pkbf16(p[2], p[3]);
      u32 w2 = pkbf16(p[4], p[5]),  w3 = pkbf16(p[6], p[7]);
      u32 w4 = pkbf16(p[8], p[9]),  w5 = pkbf16(p[10], p[11]);
      u32 w6 = pkbf16(p[12], p[13]), w7 = pkbf16(p[14], p[15]);
      asm volatile("v_permlane32_swap_b32 %0, %1" : "+v"(w0), "+v"(w2));
      asm volatile("v_permlane32_swap_b32 %0, %1" : "+v"(w1), "+v"(w3));
      asm volatile("v_permlane32_swap_b32 %0, %1" : "+v"(w4), "+v"(w6));
      asm volatile("v_permlane32_swap_b32 %0, %1" : "+v"(w5), "+v"(w7));
      const bf16x8 pb0 = __builtin_bit_cast(bf16x8, (u32x4){w0, w1, w2, w3});
      const bf16x8 pb1 = __builtin_bit_cast(bf16x8, (u32x4){w4, w5, w6, w7});

#pragma unroll
      for (int rb = 0; rb < 2; ++rb) {
        const int vrow = rb * 32 + l31;
        const int vsw  = vrow & 7;
        const bf16x8 vf0 = *(const bf16x8*)(&sV[cur][vrow * 64 + ((4 * ks + hi) ^ vsw) * 8]);
        const bf16x8 vf1 = *(const bf16x8*)(&sV[cur][vrow * 64 + ((4 * ks + 2 + hi) ^ vsw) * 8]);
        __builtin_amdgcn_s_setprio(1);
        o[rb] = MFMA32(vf0, pb0, o[rb], 0, 0, 0);
        o[rb] = MFMA32(vf1, pb1, o[rb], 0, 0, 0);
        __builtin_amdgcn_s_setprio(0);
      }
    }

    S_WAITV(0);
    bar();
  }

  lrun += __shfl_xor(lrun, 32);
  const float inv = 1.0f / lrun;
  const int bb = bh >> 4;
  const int hh = bh & 15;
  bf16* rowp = ao + (size_t)(bb * 2048 + q0 + l31) * 1024 + hh * 64;
#pragma unroll
  for (int rb = 0; rb < 2; ++rb)
#pragma unroll
    for (int r4 = 0; r4 < 4; ++r4) {
      bf16x4 pk;
#pragma unroll
      for (int g = 0; g < 4; ++g)
        pk[g] = (bf16)(o[rb][r4 * 4 + g] * inv);
      *(bf16x4*)(rowp + rb * 32 + r4 * 8 + hi * 4) = pk;
    }
}

// ---------------- launch ----------------

extern "C" void kernel_launch(void* const* d_in, const int* in_sizes, int n_in,
                              void* d_out, int out_size, void* d_ws, size_t ws_size,
                              hipStream_t stream) {
  const float* x  = (const float*)d_in[0];
  const float* Wq = (const float*)d_in[1];
  const float* bq = (const float*)d_in[2];
  const float* Wk = (const float*)d_in[3];
  const float* bk = (const float*)d_in[4];
  const float* Wv = (const float*)d_in[5];
  const float* bv = (const float*)d_in[6];
  const float* Wo = (const float*)d_in[7];
  const float* bo = (const float*)d_in[8];
  const float* gq = (const float*)d_in[9];
  const float* gk = (const float*)d_in[10];
  float* out = (float*)d_out;

  char* ws = (char*)d_ws;
  bf16* ax   = (bf16*)(ws);                    // [4096,3072]  25,165,824
  bf16* wc   = (bf16*)(ws + 25165824);         // [3072,3072]  18,874,368
  bf16* wob  = (bf16*)(ws + 44040192);         // [1024,1024]   2,097,152
  bf16* qn   = (bf16*)(ws + 46137344);         // [B,H,L,Dh]    8,388,608
  bf16* kn   = (bf16*)(ws + 54525952);         // [B,H,L,Dh]    8,388,608
  bf16* vt   = (bf16*)(ws + 62914560);         // [B,H,Dh,L]    8,388,608
  bf16* attn = (bf16*)(ws + 71303168);         // [4096,1024]   8,388,608

  prep_x_kernel<<<dim3(4096), dim3(256), 0, stream>>>(x, ax);
  prep_w_kernel<<<dim3(3072), dim3(256), 0, stream>>>(Wq, Wk, Wv, wc);
  prep_wo_kernel<<<dim3(1024), dim3(256), 0, stream>>>(Wo, wob);

  gemm_qkv_kernel<<<dim3(256), dim3(512), 0, stream>>>(
      ax, wc, bq, bk, bv, gq, gk, qn, kn, vt);

  attn_kernel<<<dim3(16, 32), dim3(256), 0, stream>>>(qn, kn, vt, attn);

  gemm_o_kernel<<<dim3(256), dim3(256), 0, stream>>>(attn, wob, bo, out);
}